// Round 1
// baseline (183.290 us; speedup 1.0000x reference)
//
#include <hip/hip_runtime.h>

// CTR-GC: N=64, C_IN=C_OUT=128, T=128, V=25, REL=16. fp32 in/out, bf16 MFMA inside.
// k_mean: coalesced LDS-staged mean over T
// k_adj : adjacency built in LDS (bf16 B-frag order) + W3 -> bf16 frag order (global)
// k_main: 2-blocks/CU version: half-K LDS staging (51 KB), W3 A-frags direct from
//         global (L2), phase C/D chunked through a small per-wave scratch that
//         overlaps the X buffer. __launch_bounds__(512,4) caps regs at 128/wave.

#define NB   64
#define CIN  128
#define COUT 128
#define TT   128
#define VV   25
#define REL  16

#define JT 25                       // j-tiles (j = t_local*25+v, 400 = 25*16)
#define XH_BYTES 51200              // half-K staging: 2 kt * 25 jt * 64 lanes * 16B
#define SCR_STRIDE 1040             // x3 scratch row stride (65*16B, de-banked)
#define SCR_WAVE   (4 * SCR_STRIDE) // 4 rows per wave chunk

typedef __attribute__((ext_vector_type(8))) short bf16x8;
typedef __attribute__((ext_vector_type(4))) float f32x4;

__device__ inline short f2bf(float f) {   // RNE f32->bf16 (finite inputs)
    unsigned u = __float_as_uint(f);
    u += 0x7fff + ((u >> 16) & 1);
    return (short)(u >> 16);
}

// ---------------- K1: mean over T (coalesced, LDS-staged) ----------------
// grid (CIN/4 = 32, N = 64), 256 thr. Block stages 4 c-rows (4 x 12.8 KB).
__launch_bounds__(256)
__global__ void k_mean(const float* __restrict__ x, float* __restrict__ xm) {
    __shared__ float tile[4 * 3200];   // 51.2 KB
    int tid = threadIdx.x;
    int c0 = blockIdx.x * 4, n = blockIdx.y;
    const float* src = x + ((size_t)n * CIN + c0) * 3200;
    for (int i = tid; i < 3200; i += 256)
        *reinterpret_cast<float4*>(&tile[i * 4]) =
            *reinterpret_cast<const float4*>(src + (size_t)i * 4);
    __syncthreads();
    if (tid < 100) {
        int cl = tid / 25, v = tid - cl * 25;
        const float* r = &tile[cl * 3200 + v];
        float s = 0.f;
#pragma unroll
        for (int t = 0; t < TT; ++t) s += r[t * 25];
        xm[((size_t)n * CIN + c0 + cl) * 25 + v] = s * (1.0f / TT);
    }
}

// ---------------- K2: adjacency -> bf16 B-fragment order (LDS-staged) ----------------
// grid (N, 4): n, o-chunk of 32. adjT region per (n,o): 2048 B.
// The 4 blocks with n==0 additionally emit W3 in bf16 A-frag order to W3f (32 KB).
__global__ void k_adj(const float* __restrict__ xm,
                      const float* __restrict__ A, const float* __restrict__ alphap,
                      const float* __restrict__ W1, const float* __restrict__ b1,
                      const float* __restrict__ W2, const float* __restrict__ b2,
                      const float* __restrict__ W4, const float* __restrict__ b4,
                      const float* __restrict__ W3, char* __restrict__ W3f,
                      char* __restrict__ adjT) {
    __shared__ char adjS[32 * 2048];   // 64 KB staging
    __shared__ float xms[CIN * VV];
    __shared__ float W1s[REL * CIN];
    __shared__ float W2s[REL * CIN];
    __shared__ float x1s[REL * VV];
    __shared__ float x2s[REL * VV];
    __shared__ float W4s[32 * REL];
    __shared__ float b4s[32];

    int tid = threadIdx.x;
    int n = blockIdx.x;
    int o0 = blockIdx.y * 32;

    // W3 -> frag order, once (n==0 blocks; 4 blocks x 512 chunks = 2048 chunks)
    if (n == 0) {
#pragma unroll
        for (int pass = 0; pass < 2; ++pass) {
            int chunk = blockIdx.y * 512 + pass * 256 + tid;
            int l = chunk & 63;
            int frag = chunk >> 6;                 // ct*4 + kt
            int ct = frag >> 2, kt = frag & 3;
            int c = ct * 16 + (l & 15);
            int kb = kt * 32 + 8 * (l >> 4);
            const float4 f0 = *reinterpret_cast<const float4*>(&W3[(size_t)c * CIN + kb]);
            const float4 f1 = *reinterpret_cast<const float4*>(&W3[(size_t)c * CIN + kb + 4]);
            bf16x8 vv;
            vv[0] = f2bf(f0.x); vv[1] = f2bf(f0.y); vv[2] = f2bf(f0.z); vv[3] = f2bf(f0.w);
            vv[4] = f2bf(f1.x); vv[5] = f2bf(f1.y); vv[6] = f2bf(f1.z); vv[7] = f2bf(f1.w);
            *reinterpret_cast<bf16x8*>(W3f + (size_t)chunk * 16) = vv;
        }
    }

    for (int i = tid; i < 16384; i += 256) reinterpret_cast<float*>(adjS)[i] = 0.f;
    for (int i = tid; i < CIN * VV; i += 256) xms[i] = xm[(size_t)n * CIN * VV + i];
    for (int i = tid; i < REL * CIN; i += 256) { W1s[i] = W1[i]; W2s[i] = W2[i]; }
    for (int i = tid; i < 32 * REL; i += 256) W4s[i] = W4[o0 * REL + i];
    if (tid < 32) b4s[tid] = b4[o0 + tid];
    __syncthreads();

    for (int task = tid; task < 2 * REL * VV; task += 256) {
        int rv = task % (REL * VV);
        int which = task / (REL * VV);
        int r = rv / VV, v = rv % VV;
        const float* Ws = which ? W2s : W1s;
        float s = 0.f;
#pragma unroll 8
        for (int c = 0; c < CIN; ++c) s = fmaf(Ws[r * CIN + c], xms[c * VV + v], s);
        s += which ? b2[r] : b1[r];
        (which ? x2s : x1s)[rv] = s;
    }
    __syncthreads();

    float alpha = alphap[0];
    for (int p = tid; p < VV * VV; p += 256) {
        int v = p / VV, u = p % VV;
        float d[REL];
#pragma unroll
        for (int r = 0; r < REL; ++r) d[r] = tanhf(x1s[r * VV + v] - x2s[r * VV + u]);
        float Avu = A[v * VV + u];
        // B-frag offset: b_frag[b] = adj[v = 8*(l>>4)+b][u = ut*16 + (l&15)]
        int off = (u >> 4) * 1024 + (((u & 15) + 16 * (v >> 3)) * 16) + (v & 7) * 2;
        for (int oo = 0; oo < 32; ++oo) {
            float s = 0.f;
#pragma unroll
            for (int r = 0; r < REL; ++r) s = fmaf(W4s[oo * REL + r], d[r], s);
            float val = alpha * (s + b4s[oo]) + Avu;
            *(short*)(adjS + oo * 2048 + off) = f2bf(val);
        }
    }
    __syncthreads();

    float4* dst = reinterpret_cast<float4*>(adjT + (size_t)(n * COUT + o0) * 2048);
    const float4* src = reinterpret_cast<const float4*>(adjS);
    for (int i = tid; i < 4096; i += 256) dst[i] = src[i];
}

// ---------------- K3: two fused MFMA GEMMs (2 blocks/CU) ----------------
// grid (T/16 = 8, N = 64), 512 threads (8 waves). Wave w owns c-tile ct = w.
__launch_bounds__(512, 4)
__global__ void k_main(const float* __restrict__ x, const char* __restrict__ W3f,
                       const float* __restrict__ b3, const char* __restrict__ adjT,
                       float* __restrict__ out) {
    __shared__ __align__(16) char lds[XH_BYTES];   // 51.2 KB

    int tid = threadIdx.x;
    int tb = blockIdx.x, n = blockIdx.y;
    int lane = tid & 63, w = tid >> 6;
    int g = lane >> 4, lr = lane & 15;

    const float* xb = x + (size_t)n * (CIN * TT * VV) + tb * (16 * VV);

    f32x4 acc[JT];
#pragma unroll
    for (int jt = 0; jt < JT; ++jt) acc[jt] = f32x4{0.f, 0.f, 0.f, 0.f};

#pragma unroll
    for (int h = 0; h < 2; ++h) {
        // ---- stage half h (kt = 2h, 2h+1): 3200 chunks of 16 B ----
#pragma unroll
        for (int q = 0; q < 7; ++q) {
            int chunk = tid + q * 512;
            if (chunk < 3200) {
                int l = chunk & 63;
                int frag = chunk >> 6;                 // kk*25 + jt
                int kk = (frag >= JT) ? 1 : 0;
                int jt = frag - kk * JT;
                int j = jt * 16 + (l & 15);
                int kb = (h * 2 + kk) * 32 + 8 * (l >> 4);
                const float* p = xb + (size_t)kb * (TT * VV) + j;
                bf16x8 v;
#pragma unroll
                for (int b = 0; b < 8; ++b) v[b] = f2bf(p[(size_t)b * (TT * VV)]);
                *reinterpret_cast<bf16x8*>(lds + (size_t)chunk * 16) = v;
            }
        }
        __syncthreads();

        // ---- GEMM1 on this half's two k-tiles ----
#pragma unroll
        for (int kk = 0; kk < 2; ++kk) {
            int kt = h * 2 + kk;
            bf16x8 a = *reinterpret_cast<const bf16x8*>(
                W3f + (size_t)((w * 4 + kt) * 64 + lane) * 16);
#pragma unroll
            for (int jt = 0; jt < JT; ++jt) {
                bf16x8 bx = *reinterpret_cast<const bf16x8*>(
                    lds + (size_t)((kk * JT + jt) * 64 + lane) * 16);
                acc[jt] = __builtin_amdgcn_mfma_f32_16x16x32_bf16(a, bx, acc[jt], 0, 0, 0);
            }
        }
        __syncthreads();   // all waves done reading before restage / scratch reuse
    }

    // ---- Phase C/D: 4 chunks of 4 c-rows per wave, through per-wave scratch ----
    const char* adjTb = adjT + (size_t)(n * COUT) * 2048;
    int t0 = tb * 16;
    char* scr = lds + w * SCR_WAVE;
#pragma unroll
    for (int r = 0; r < 4; ++r) {
        // repack row (w*16 + 4g + r) -> scr + g*SCR_STRIDE (A-frag order)
        float bvr = b3[w * 16 + 4 * g + r];
#pragma unroll
        for (int jt = 0; jt < JT; ++jt) {
            int j = jt * 16 + lr;
            int t = j / 25, v = j - t * 25;
            int off = (t + 16 * (v >> 3)) * 16 + (v & 7) * 2;
            *(short*)(scr + g * SCR_STRIDE + off) = f2bf(acc[jt][r] + bvr);
        }
        // zero v = 25..31 pad slots for this chunk's 4 rows (4*112 = 448 shorts)
#pragma unroll
        for (int z = 0; z < 7; ++z) {
            int idx = lane + z * 64;
            int gg = idx / 112;
            int rem = idx - gg * 112;
            int t = rem / 7, qq = rem - t * 7;
            *(short*)(scr + gg * SCR_STRIDE + (t + 48) * 16 + 2 + qq * 2) = 0;
        }
        // GEMM2 for the 4 rows of this chunk (same-wave LDS order, no barrier)
#pragma unroll
        for (int gg = 0; gg < 4; ++gg) {
            int c = w * 16 + 4 * gg + r;
            bf16x8 a = *reinterpret_cast<const bf16x8*>(scr + gg * SCR_STRIDE + lane * 16);
            const bf16x8* bp = reinterpret_cast<const bf16x8*>(adjTb + (size_t)c * 2048);
            bf16x8 b0 = bp[lane];
            bf16x8 b1 = bp[64 + lane];
            f32x4 z = {0.f, 0.f, 0.f, 0.f};
            f32x4 d0 = __builtin_amdgcn_mfma_f32_16x16x32_bf16(a, b0, z, 0, 0, 0);
            f32x4 d1 = __builtin_amdgcn_mfma_f32_16x16x32_bf16(a, b1, z, 0, 0, 0);
            float* ob = out + ((size_t)(n * COUT + c) * TT + t0) * VV;
#pragma unroll
            for (int rr = 0; rr < 4; ++rr) {
                int t = 4 * g + rr;
                ob[(size_t)t * VV + lr] = d0[rr];
                if (lr < 9) ob[(size_t)t * VV + 16 + lr] = d1[rr];
            }
        }
    }
}

extern "C" void kernel_launch(void* const* d_in, const int* in_sizes, int n_in,
                              void* d_out, int out_size, void* d_ws, size_t ws_size,
                              hipStream_t stream) {
    const float* x     = (const float*)d_in[0];
    const float* A     = (const float*)d_in[1];
    const float* alpha = (const float*)d_in[2];
    const float* W1    = (const float*)d_in[3];
    const float* b1    = (const float*)d_in[4];
    const float* W2    = (const float*)d_in[5];
    const float* b2    = (const float*)d_in[6];
    const float* W3    = (const float*)d_in[7];
    const float* b3    = (const float*)d_in[8];
    const float* W4    = (const float*)d_in[9];
    const float* b4    = (const float*)d_in[10];
    float* out = (float*)d_out;

    float* xm  = (float*)d_ws;                      // 819,200 B
    char* adjT = (char*)d_ws + 819200;              // 64*128*2048 = 16,777,216 B
    char* W3f  = (char*)d_ws + 819200 + 16777216;   // 32,768 B

    k_mean<<<dim3(CIN / 4, NB), 256, 0, stream>>>(x, xm);
    k_adj<<<dim3(NB, 4), 256, 0, stream>>>(xm, A, alpha, W1, b1, W2, b2, W4, b4,
                                           W3, W3f, adjT);
    k_main<<<dim3(TT / 16, NB), 512, 0, stream>>>(x, W3f, b3, adjT, out);
}

// Round 2
// 115.380 us; speedup vs baseline: 1.5886x; 1.5886x over previous
//
#include <hip/hip_runtime.h>

// CTR-GC: N=64, C_IN=C_OUT=128, T=128, V=25, REL=16. fp32 in/out, bf16 MFMA inside.
// k_mean: coalesced LDS-staged mean over T
// k_adj : adjacency built in LDS (bf16 B-frag order) + W3 -> bf16 frag order (global)
// k_main: 1024 threads / 16 waves. Wave w owns (ct = w>>1, j-half = w&1) so the
//         GEMM1 accumulator is 13 frags (52 regs) not 25 (100) -> fits 128-reg
//         budget at 4 waves/SIMD without spill. Full-K X staging (102.4 KB),
//         x3 repack into a 133.1 KB union buffer, GEMM2 = 8 c-rows/wave.

#define NB   64
#define CIN  128
#define COUT 128
#define TT   128
#define VV   25
#define REL  16

#define JT 25                        // j-tiles (j = t_local*25+v, 400 = 25*16)
#define KT 4                         // k-tiles of 32
#define XF_BYTES (JT * KT * 1024)    // 102,400 X frag staging
#define X3_STRIDE 1040               // x3 row stride (65*16B, de-banked)
#define LDS_BYTES (COUT * X3_STRIDE) // 133,120 (union: X frags alive only pre-repack)

typedef __attribute__((ext_vector_type(8))) short bf16x8;
typedef __attribute__((ext_vector_type(4))) float f32x4;

__device__ inline short f2bf(float f) {   // RNE f32->bf16 (finite inputs)
    unsigned u = __float_as_uint(f);
    u += 0x7fff + ((u >> 16) & 1);
    return (short)(u >> 16);
}

// ---------------- K1: mean over T (coalesced, LDS-staged) ----------------
// grid (CIN/4 = 32, N = 64), 256 thr. Block stages 4 c-rows (4 x 12.8 KB).
__launch_bounds__(256)
__global__ void k_mean(const float* __restrict__ x, float* __restrict__ xm) {
    __shared__ float tile[4 * 3200];   // 51.2 KB
    int tid = threadIdx.x;
    int c0 = blockIdx.x * 4, n = blockIdx.y;
    const float* src = x + ((size_t)n * CIN + c0) * 3200;
    for (int i = tid; i < 3200; i += 256)
        *reinterpret_cast<float4*>(&tile[i * 4]) =
            *reinterpret_cast<const float4*>(src + (size_t)i * 4);
    __syncthreads();
    if (tid < 100) {
        int cl = tid / 25, v = tid - cl * 25;
        const float* r = &tile[cl * 3200 + v];
        float s = 0.f;
#pragma unroll
        for (int t = 0; t < TT; ++t) s += r[t * 25];
        xm[((size_t)n * CIN + c0 + cl) * 25 + v] = s * (1.0f / TT);
    }
}

// ---------------- K2: adjacency -> bf16 B-fragment order (LDS-staged) ----------------
// grid (N, 4): n, o-chunk of 32. adjT region per (n,o): 2048 B.
// The 4 blocks with n==0 additionally emit W3 in bf16 A-frag order to W3f (32 KB).
__global__ void k_adj(const float* __restrict__ xm,
                      const float* __restrict__ A, const float* __restrict__ alphap,
                      const float* __restrict__ W1, const float* __restrict__ b1,
                      const float* __restrict__ W2, const float* __restrict__ b2,
                      const float* __restrict__ W4, const float* __restrict__ b4,
                      const float* __restrict__ W3, char* __restrict__ W3f,
                      char* __restrict__ adjT) {
    __shared__ char adjS[32 * 2048];   // 64 KB staging
    __shared__ float xms[CIN * VV];
    __shared__ float W1s[REL * CIN];
    __shared__ float W2s[REL * CIN];
    __shared__ float x1s[REL * VV];
    __shared__ float x2s[REL * VV];
    __shared__ float W4s[32 * REL];
    __shared__ float b4s[32];

    int tid = threadIdx.x;
    int n = blockIdx.x;
    int o0 = blockIdx.y * 32;

    // W3 -> frag order, once (n==0 blocks; 4 blocks x 512 chunks = 2048 chunks)
    if (n == 0) {
#pragma unroll
        for (int pass = 0; pass < 2; ++pass) {
            int chunk = blockIdx.y * 512 + pass * 256 + tid;
            int l = chunk & 63;
            int frag = chunk >> 6;                 // ct*4 + kt
            int ct = frag >> 2, kt = frag & 3;
            int c = ct * 16 + (l & 15);
            int kb = kt * 32 + 8 * (l >> 4);
            const float4 f0 = *reinterpret_cast<const float4*>(&W3[(size_t)c * CIN + kb]);
            const float4 f1 = *reinterpret_cast<const float4*>(&W3[(size_t)c * CIN + kb + 4]);
            bf16x8 vv;
            vv[0] = f2bf(f0.x); vv[1] = f2bf(f0.y); vv[2] = f2bf(f0.z); vv[3] = f2bf(f0.w);
            vv[4] = f2bf(f1.x); vv[5] = f2bf(f1.y); vv[6] = f2bf(f1.z); vv[7] = f2bf(f1.w);
            *reinterpret_cast<bf16x8*>(W3f + (size_t)chunk * 16) = vv;
        }
    }

    for (int i = tid; i < 16384; i += 256) reinterpret_cast<float*>(adjS)[i] = 0.f;
    for (int i = tid; i < CIN * VV; i += 256) xms[i] = xm[(size_t)n * CIN * VV + i];
    for (int i = tid; i < REL * CIN; i += 256) { W1s[i] = W1[i]; W2s[i] = W2[i]; }
    for (int i = tid; i < 32 * REL; i += 256) W4s[i] = W4[o0 * REL + i];
    if (tid < 32) b4s[tid] = b4[o0 + tid];
    __syncthreads();

    for (int task = tid; task < 2 * REL * VV; task += 256) {
        int rv = task % (REL * VV);
        int which = task / (REL * VV);
        int r = rv / VV, v = rv % VV;
        const float* Ws = which ? W2s : W1s;
        float s = 0.f;
#pragma unroll 8
        for (int c = 0; c < CIN; ++c) s = fmaf(Ws[r * CIN + c], xms[c * VV + v], s);
        s += which ? b2[r] : b1[r];
        (which ? x2s : x1s)[rv] = s;
    }
    __syncthreads();

    float alpha = alphap[0];
    for (int p = tid; p < VV * VV; p += 256) {
        int v = p / VV, u = p % VV;
        float d[REL];
#pragma unroll
        for (int r = 0; r < REL; ++r) d[r] = tanhf(x1s[r * VV + v] - x2s[r * VV + u]);
        float Avu = A[v * VV + u];
        // B-frag offset: b_frag[b] = adj[v = 8*(l>>4)+b][u = ut*16 + (l&15)]
        int off = (u >> 4) * 1024 + (((u & 15) + 16 * (v >> 3)) * 16) + (v & 7) * 2;
        for (int oo = 0; oo < 32; ++oo) {
            float s = 0.f;
#pragma unroll
            for (int r = 0; r < REL; ++r) s = fmaf(W4s[oo * REL + r], d[r], s);
            float val = alpha * (s + b4s[oo]) + Avu;
            *(short*)(adjS + oo * 2048 + off) = f2bf(val);
        }
    }
    __syncthreads();

    float4* dst = reinterpret_cast<float4*>(adjT + (size_t)(n * COUT + o0) * 2048);
    const float4* src = reinterpret_cast<const float4*>(adjS);
    for (int i = tid; i < 4096; i += 256) dst[i] = src[i];
}

// ---------------- K3: two fused MFMA GEMMs (16 waves, split-j acc) ----------------
// grid (T/16 = 8, N = 64), 1024 threads. Wave w: ct = w>>1, j-half = w&1.
__launch_bounds__(1024)
__global__ void k_main(const float* __restrict__ x, const char* __restrict__ W3f,
                       const float* __restrict__ b3, const char* __restrict__ adjT,
                       float* __restrict__ out) {
    __shared__ __align__(16) char lds[LDS_BYTES];   // 133,120 B

    int tid = threadIdx.x;
    int tb = blockIdx.x, n = blockIdx.y;
    int lane = tid & 63, w = tid >> 6;
    int g = lane >> 4, lr = lane & 15;
    int ct = w >> 1, jh = w & 1;
    int jt0 = jh ? 13 : 0;
    int njt = jh ? 12 : 13;

    const float* xb = x + (size_t)n * (CIN * TT * VV) + tb * (16 * VV);

    // ---- Phase A: regs-first gather of X into bf16 frag order (6400 chunks) ----
    bf16x8 xr[7];
#pragma unroll
    for (int q = 0; q < 7; ++q) {
        int chunk = tid + q * 1024;
        if (chunk < JT * KT * 64) {
            int l = chunk & 63;
            int frag = chunk >> 6;                 // kt*25 + jt
            int kt = frag / JT, jt = frag % JT;
            int j = jt * 16 + (l & 15);
            int kb = kt * 32 + 8 * (l >> 4);
            const float* p = xb + (size_t)kb * (TT * VV) + j;
#pragma unroll
            for (int b = 0; b < 8; ++b) xr[q][b] = f2bf(p[(size_t)b * (TT * VV)]);
        }
    }
#pragma unroll
    for (int q = 0; q < 7; ++q) {
        int chunk = tid + q * 1024;
        if (chunk < JT * KT * 64)
            *reinterpret_cast<bf16x8*>(lds + (size_t)chunk * 16) = xr[q];
    }
    __syncthreads();

    // ---- Phase B: GEMM1  x3 = W3 @ X  (this wave: 16 c-rows x its j-half) ----
    f32x4 acc[13];
#pragma unroll
    for (int u = 0; u < 13; ++u) acc[u] = f32x4{0.f, 0.f, 0.f, 0.f};
#pragma unroll
    for (int kt = 0; kt < KT; ++kt) {
        bf16x8 a = *reinterpret_cast<const bf16x8*>(
            W3f + (size_t)((ct * 4 + kt) * 64 + lane) * 16);
#pragma unroll
        for (int u = 0; u < 13; ++u) {
            if (u < njt) {
                int jt = jt0 + u;
                bf16x8 bx = *reinterpret_cast<const bf16x8*>(
                    lds + (size_t)((kt * JT + jt) * 64 + lane) * 16);
                acc[u] = __builtin_amdgcn_mfma_f32_16x16x32_bf16(a, bx, acc[u], 0, 0, 0);
            }
        }
    }
    __syncthreads();   // all Xf reads done before repack overwrites

    // ---- Phase C: x3 (+b3) -> bf16 A-frag order, full 128-row buffer ----
    int cbase = ct * 16 + 4 * g;
    float bv[4];
#pragma unroll
    for (int r = 0; r < 4; ++r) bv[r] = b3[cbase + r];
#pragma unroll
    for (int u = 0; u < 13; ++u) {
        if (u < njt) {
            int j = (jt0 + u) * 16 + lr;
            int t = j / 25, v = j - t * 25;
            int off = (t + 16 * (v >> 3)) * 16 + (v & 7) * 2;
#pragma unroll
            for (int r = 0; r < 4; ++r)
                *(short*)(lds + (size_t)(cbase + r) * X3_STRIDE + off) =
                    f2bf(acc[u][r] + bv[r]);
        }
    }
    // zero v = 25..31 pad slots: 128 rows x 112 shorts = 14336 = 14 * 1024
#pragma unroll
    for (int z = 0; z < 14; ++z) {
        int idx = tid + z * 1024;
        int c = idx / 112;
        int rem = idx - c * 112;
        int t = rem / 7, qq = rem - t * 7;
        *(short*)(lds + (size_t)c * X3_STRIDE + (t + 48) * 16 + 2 + qq * 2) = 0;
    }
    __syncthreads();   // rows assembled by wave pairs -> block barrier

    // ---- Phase D: GEMM2  out = x3 @ adj  (8 c-rows per wave) ----
    const char* adjTb = adjT + (size_t)(n * COUT) * 2048;
    int t0 = tb * 16;
#pragma unroll
    for (int cc = 0; cc < 8; ++cc) {
        int c = w * 8 + cc;
        bf16x8 a = *reinterpret_cast<const bf16x8*>(lds + (size_t)c * X3_STRIDE + lane * 16);
        const bf16x8* bp = reinterpret_cast<const bf16x8*>(adjTb + (size_t)c * 2048);
        bf16x8 b0 = bp[lane];
        bf16x8 b1 = bp[64 + lane];
        f32x4 z = {0.f, 0.f, 0.f, 0.f};
        f32x4 d0 = __builtin_amdgcn_mfma_f32_16x16x32_bf16(a, b0, z, 0, 0, 0);
        f32x4 d1 = __builtin_amdgcn_mfma_f32_16x16x32_bf16(a, b1, z, 0, 0, 0);
        float* ob = out + ((size_t)(n * COUT + c) * TT + t0) * VV;
#pragma unroll
        for (int rr = 0; rr < 4; ++rr) {
            int t = 4 * g + rr;
            ob[(size_t)t * VV + lr] = d0[rr];
            if (lr < 9) ob[(size_t)t * VV + 16 + lr] = d1[rr];
        }
    }
}

extern "C" void kernel_launch(void* const* d_in, const int* in_sizes, int n_in,
                              void* d_out, int out_size, void* d_ws, size_t ws_size,
                              hipStream_t stream) {
    const float* x     = (const float*)d_in[0];
    const float* A     = (const float*)d_in[1];
    const float* alpha = (const float*)d_in[2];
    const float* W1    = (const float*)d_in[3];
    const float* b1    = (const float*)d_in[4];
    const float* W2    = (const float*)d_in[5];
    const float* b2    = (const float*)d_in[6];
    const float* W3    = (const float*)d_in[7];
    const float* b3    = (const float*)d_in[8];
    const float* W4    = (const float*)d_in[9];
    const float* b4    = (const float*)d_in[10];
    float* out = (float*)d_out;

    float* xm  = (float*)d_ws;                      // 819,200 B
    char* adjT = (char*)d_ws + 819200;              // 64*128*2048 = 16,777,216 B
    char* W3f  = (char*)d_ws + 819200 + 16777216;   // 32,768 B

    k_mean<<<dim3(CIN / 4, NB), 256, 0, stream>>>(x, xm);
    k_adj<<<dim3(NB, 4), 256, 0, stream>>>(xm, A, alpha, W1, b1, W2, b2, W4, b4,
                                           W3, W3f, adjT);
    k_main<<<dim3(TT / 16, NB), 1024, 0, stream>>>(x, W3f, b3, adjT, out);
}